// Round 5
// baseline (85.183 us; speedup 1.0000x reference)
//
#include <hip/hip_runtime.h>
#include <hip/hip_fp16.h>

// Radon3D loss on MI355X — project the DIFFERENCE volume (radon is linear).
// Geometry (D=H=W=64, 120 angles over [0,120] deg): L=91, pad top=left=13.
//   ix(i,j) = 45*c*linj + 32 + 45*s - s*i,  iy(i,j) = 45*s*linj + 32 - 45*c + c*i
//   (unit steps in i: the 0.5*(L-1) unnormalization cancels the linspace step)
// TWO 4-byte canvases (P0: half2 diffs slices s0,s0+1; P1: s0+2,s0+3), each
// with ODD word stride 69 -> x-adjacent lanes stride 1 word, y-adjacent
// stride 69 (odd mod 32) -> conflict-free both ways (8B cells were 4-way).
// Corner pairs (0,+1) and (+69,+70) merge into ds_read2_b32.
// Coords shifted +1 (nonneg) and clamped to [0,65]: out-of-support samples
// hit the zero border with zero weight == map_coordinates cval=0.
#define DD 64
#define NA 120
#define NS 64
#define LL 91
#define PS 67
#define PSTR 69               // ODD word stride -> no structured bank conflicts
#define NCELL (PS * PSTR)     // 4623 words = 18.5 KB per canvas
#define NSL 4                 // slices per block (2 per canvas)
#define NANG 4                // angles per block
#define JT 96                 // j-lanes per angle (91 active)
#define NTHR (NANG * JT)      // 384
#define NBLKS ((NS / NSL) * (NA / NANG))   // 16 * 30 = 480

static __device__ __forceinline__ __half2 u2h(unsigned int u) {
    union { unsigned int u; __half2 h; } v; v.u = u; return v.h;
}
static __device__ __forceinline__ unsigned int h2u(__half2 h) {
    union { __half2 h; unsigned int u; } v; v.h = h; return v.u;
}

__global__ __launch_bounds__(NTHR, 4) void radon_loss_kernel(
    const float* __restrict__ vout, const float* __restrict__ vgt,
    float* __restrict__ out)
{
    __shared__ unsigned int P0[NCELL];   // slices s0, s0+1
    __shared__ unsigned int P1[NCELL];   // slices s0+2, s0+3
    __shared__ float wsum[NTHR / 64];

    const int bid = blockIdx.x;
    const int sp = bid / (NA / NANG);          // slice group 0..15
    const int ap = bid - sp * (NA / NANG);     // angle group 0..29
    const int s0 = sp * NSL;
    const int t = threadIdx.x;

    // 1) zero both padded canvases
    for (int idx = t; idx < NCELL; idx += NTHR) {
        P0[idx] = 0u;
        P1[idx] = 0u;
    }
    __syncthreads();

    // 2) stage fp16 diffs of 4 slices: im_s[d][w] = vol[0,0,d,s,w]
    for (int idx = t; idx < DD * DD; idx += NTHR) {
        const int d = idx >> 6, w = idx & 63;
        const int g = d * 4096 + s0 * 64 + w;
        const float d0 = vout[g]       - vgt[g];
        const float d1 = vout[g + 64]  - vgt[g + 64];
        const float d2 = vout[g + 128] - vgt[g + 128];
        const float d3 = vout[g + 192] - vgt[g + 192];
        const int ci = (d + 1) * PSTR + (w + 1);
        P0[ci] = h2u(__floats2half2_rn(d0, d1));
        P1[ci] = h2u(__floats2half2_rn(d2, d3));
    }
    __syncthreads();

    // 3) projection: thread = (angle slot, column j); full i-range per thread
    const int ja = t / JT;
    const int j  = t - ja * JT;
    const int a  = ap * NANG + ja;
    const float theta = (float)a * (float)(3.14159265358979323846 * 120.0 / 119.0 / 180.0);
    const float c = cosf(theta), sn = sinf(theta);

    float val = 0.f;
    if (j < LL) {
        const float linj = fmaf((float)j, 2.0f / 90.0f, -1.0f);
        // +1 shift: coords in [0,65] after clamp; canvas row/col 0 is border
        const float bx1 = fmaf(c,  linj, 1.0f) * 45.0f - 12.0f + 45.0f * sn;
        const float by1 = fmaf(sn, linj, 1.0f) * 45.0f - 12.0f - 45.0f * c;
        __half2 acc0 = __floats2half2_rn(0.f, 0.f);
        __half2 acc1 = acc0;
        for (int i = 0; i < LL; ++i) {
            // independent per-iteration coords -> deep compiler pipelining
            const float xs = fminf(fmaxf(fmaf(-(float)i, sn, bx1), 0.0f), 65.0f);
            const float ys = fminf(fmaxf(fmaf( (float)i, c,  by1), 0.0f), 65.0f);
            const int ix = (int)xs;            // trunc == floor (nonneg)
            const int iy = (int)ys;
            const float wx = xs - (float)ix;
            const float wy = ys - (float)iy;
            const __half2 wx2 = __float2half2_rn(wx);
            const __half2 wy2 = __float2half2_rn(wy);
            const int ci = iy * PSTR + ix;     // mad_u32_u24
            const unsigned int a00 = P0[ci],        a01 = P0[ci + 1];
            const unsigned int a10 = P0[ci + PSTR], a11 = P0[ci + PSTR + 1];
            const unsigned int b00 = P1[ci],        b01 = P1[ci + 1];
            const unsigned int b10 = P1[ci + PSTR], b11 = P1[ci + PSTR + 1];
            const __half2 t0 = __hfma2(wx2, __hsub2(u2h(a01), u2h(a00)), u2h(a00));
            const __half2 bb0 = __hfma2(wx2, __hsub2(u2h(a11), u2h(a10)), u2h(a10));
            acc0 = __hadd2(acc0, __hfma2(wy2, __hsub2(bb0, t0), t0));
            const __half2 t1 = __hfma2(wx2, __hsub2(u2h(b01), u2h(b00)), u2h(b00));
            const __half2 bb1 = __hfma2(wx2, __hsub2(u2h(b11), u2h(b10)), u2h(b10));
            acc1 = __hadd2(acc1, __hfma2(wy2, __hsub2(bb1, t1), t1));
        }
        const float2 a0f = __half22float2(acc0);
        const float2 a1f = __half22float2(acc1);
        val = fabsf(a0f.x) + fabsf(a0f.y) + fabsf(a1f.x) + fabsf(a1f.y);
    }

    // 4) block reduction + one scaled atomic per block
    #pragma unroll
    for (int off = 32; off > 0; off >>= 1)
        val += __shfl_down(val, off);
    const int wave = t >> 6, lane = t & 63;
    if (lane == 0) wsum[wave] = val;
    __syncthreads();
    if (t == 0) {
        float v = 0.f;
        #pragma unroll
        for (int wv = 0; wv < NTHR / 64; ++wv) v += wsum[wv];
        atomicAdd(out, v * (1.0f / (float)(NA * LL)));
    }
}

extern "C" void kernel_launch(void* const* d_in, const int* in_sizes, int n_in,
                              void* d_out, int out_size, void* d_ws, size_t ws_size,
                              hipStream_t stream) {
    const float* vout = (const float*)d_in[0];
    const float* vgt  = (const float*)d_in[1];
    float* out = (float*)d_out;

    hipMemsetAsync(out, 0, sizeof(float), stream);
    radon_loss_kernel<<<NBLKS, NTHR, 0, stream>>>(vout, vgt, out);
}